// Round 1
// baseline (346.516 us; speedup 1.0000x reference)
//
#include <hip/hip_runtime.h>
#include <cstddef>
#include <cstdint>

typedef unsigned short u16;
typedef __attribute__((ext_vector_type(8))) unsigned short ushort8;
typedef __attribute__((ext_vector_type(8))) short bf16x8;   // 8 bf16 bit-patterns (4 VGPRs)
typedef __attribute__((ext_vector_type(4))) float f32x4;

#define DEV __device__ __forceinline__

DEV u16 f2bf(float f){
  uint32_t u = __builtin_bit_cast(uint32_t, f);
  u += 0x7FFFu + ((u >> 16) & 1u);          // RNE
  return (u16)(u >> 16);
}
DEV float silu_f(float x){ return x / (1.f + __expf(-x)); }

// ---------------- transpose fp32 [R][C] -> bf16 [C][R] ----------------
__global__ __launch_bounds__(256) void transpose_bf16_k(const float* __restrict__ in,
                                                        u16* __restrict__ out, int R, int C){
  __shared__ u16 tile[32][33];
  int c0 = blockIdx.x * 32, r0 = blockIdx.y * 32;
  int tx = threadIdx.x, ty = threadIdx.y;     // block (32,8)
  #pragma unroll
  for (int k = 0; k < 4; ++k){
    int r = r0 + ty + k*8, c = c0 + tx;
    float v = (c < C) ? in[(size_t)r * C + c] : 0.f;
    tile[ty + k*8][tx] = f2bf(v);
  }
  __syncthreads();
  #pragma unroll
  for (int k = 0; k < 4; ++k){
    int oc = c0 + ty + k*8, orr = r0 + tx;
    if (oc < C) out[(size_t)oc * R + orr] = tile[tx][ty + k*8];
  }
}

// ---------------- generic bf16-MFMA GEMM ----------------
// C[M,N] = A_fp32[M,K] @ B, B supplied pre-transposed as bf16 [N][K] (ldb=K).
// A is converted fp32->bf16 during LDS staging.
// MODE: 0 = atomicAdd into out0 (256-wide; split-K via blockIdx.z)
//       1 = +bias, ReLU, LayerNorm(256) -> out0 fp32
//       2 = split store: cols<512 -> out0, else -> out1 (both 512-wide)
//       3 = store cols<48 -> out0 (48-wide)
template<int MODE, int TM, int NT>
__global__ __launch_bounds__(256) void gemm_k(const float* __restrict__ A, int lda,
    const u16* __restrict__ Bt, int ldb, int kchunk,
    float* __restrict__ out0, float* __restrict__ out1,
    const float* __restrict__ bias, const float* __restrict__ lng, const float* __restrict__ lnb)
{
  constexpr int WN = NT / 4, MI = TM / 16, NI = WN / 16;
  extern __shared__ char smem[];
  u16* As = (u16*)smem;                 // TM x 40 (pad 40: 80B rows, 16B-aligned, spreads banks)
  u16* Bs = As + TM * 40;               // NT x 40
  const int tid = threadIdx.x, wave = tid >> 6, lane = tid & 63;
  const int lq = lane >> 4, lr = lane & 15;
  const int m0 = blockIdx.x * TM, n0g = blockIdx.y * NT;
  const int k0base = blockIdx.z * kchunk;

  f32x4 acc[MI][NI];
  #pragma unroll
  for (int i = 0; i < MI; ++i)
    #pragma unroll
    for (int j = 0; j < NI; ++j) acc[i][j] = f32x4{0.f, 0.f, 0.f, 0.f};

  for (int kk = 0; kk < kchunk; kk += 32){
    const int k0 = k0base + kk;
    // stage A: TM x 32 fp32 -> bf16, 8 elems/thread
    for (int i = tid * 8; i < TM * 32; i += 256 * 8){
      int row = i >> 5, ko = i & 31;
      const float* ap = A + (size_t)(m0 + row) * lda + k0 + ko;
      f32x4 f0 = *(const f32x4*)ap;
      f32x4 f1 = *(const f32x4*)(ap + 4);
      ushort8 o;
      #pragma unroll
      for (int j = 0; j < 4; ++j) o[j] = f2bf(f0[j]);
      #pragma unroll
      for (int j = 0; j < 4; ++j) o[4 + j] = f2bf(f1[j]);
      *(ushort8*)(As + row * 40 + ko) = o;
    }
    // stage B: NT rows x 32 bf16, one row/thread
    for (int n = tid; n < NT; n += 256){
      const ushort8* bp = (const ushort8*)(Bt + (size_t)(n0g + n) * ldb + k0);
      ushort8* dst = (ushort8*)(Bs + n * 40);
      dst[0] = bp[0]; dst[1] = bp[1]; dst[2] = bp[2]; dst[3] = bp[3];
    }
    __syncthreads();
    bf16x8 af[MI], bfr[NI];
    #pragma unroll
    for (int mi = 0; mi < MI; ++mi)
      af[mi] = *(const bf16x8*)(As + (mi * 16 + lr) * 40 + lq * 8);
    #pragma unroll
    for (int ni = 0; ni < NI; ++ni)
      bfr[ni] = *(const bf16x8*)(Bs + (wave * WN + ni * 16 + lr) * 40 + lq * 8);
    #pragma unroll
    for (int mi = 0; mi < MI; ++mi)
      #pragma unroll
      for (int ni = 0; ni < NI; ++ni)
        acc[mi][ni] = __builtin_amdgcn_mfma_f32_16x16x32_bf16(af[mi], bfr[ni], acc[mi][ni], 0, 0, 0);
    __syncthreads();
  }

  if constexpr (MODE == 1){
    float* Hs  = (float*)(smem + TM * 80 + NT * 80);   // TM x 257 (pad kills bank conflicts)
    float* mus = Hs + TM * 257;
    float* rss = mus + TM;
    #pragma unroll
    for (int mi = 0; mi < MI; ++mi)
      #pragma unroll
      for (int ni = 0; ni < NI; ++ni)
        #pragma unroll
        for (int r = 0; r < 4; ++r){
          int row_l = mi*16 + lq*4 + r;
          int col_l = wave*WN + ni*16 + lr;
          Hs[row_l*257 + col_l] = fmaxf(acc[mi][ni][r] + bias[col_l], 0.f);
        }
    __syncthreads();
    if (tid < TM){
      float s = 0.f, s2 = 0.f;
      for (int c = 0; c < 256; ++c){ float v = Hs[tid*257 + c]; s += v; s2 += v*v; }
      float mu  = s * (1.f/256.f);
      float var = s2 * (1.f/256.f) - mu*mu;
      mus[tid] = mu; rss[tid] = rsqrtf(var + 1e-5f);
    }
    __syncthreads();
    for (int idx = tid; idx < TM*256; idx += 256){
      int r = idx >> 8, c = idx & 255;
      float v = (Hs[r*257 + c] - mus[r]) * rss[r] * lng[c] + lnb[c];
      out0[(size_t)(m0 + r) * 256 + c] = v;
    }
  } else {
    #pragma unroll
    for (int mi = 0; mi < MI; ++mi)
      #pragma unroll
      for (int ni = 0; ni < NI; ++ni)
        #pragma unroll
        for (int r = 0; r < 4; ++r){
          float v = acc[mi][ni][r];
          int row  = m0 + mi*16 + lq*4 + r;
          int gcol = n0g + wave*WN + ni*16 + lr;
          if constexpr (MODE == 0){
            atomicAdd(out0 + (size_t)row * 256 + gcol, v);
          } else if constexpr (MODE == 2){
            if (gcol < 512) out0[(size_t)row * 512 + gcol] = v;
            else            out1[(size_t)row * 512 + gcol - 512] = v;
          } else {
            if (gcol < 48)  out0[(size_t)row * 48 + gcol] = v;
          }
        }
  }
}

// ---------------- depthwise causal conv (k=4) + silu ----------------
__global__ __launch_bounds__(256) void conv_silu_k(const float* __restrict__ xc,
    const float* __restrict__ cw, const float* __restrict__ cb, float* __restrict__ u){
  int idx = blockIdx.x * 256 + threadIdx.x;
  int t = idx >> 9, d = idx & 511;
  float acc = cb[d];
  #pragma unroll
  for (int k = 0; k < 4; ++k){
    int ts = t + k - 3;
    if (ts >= 0) acc += xc[(size_t)ts * 512 + d] * cw[d * 4 + k];
  }
  u[idx] = silu_f(acc);
}

// ---------------- dt = softplus(dbc[:, :16] @ w_dt + b_dt) ----------------
__global__ __launch_bounds__(256) void dt_k(const float* __restrict__ dbc,
    const float* __restrict__ w_dt, const float* __restrict__ b_dt, float* __restrict__ dt){
  int idx = blockIdx.x * 256 + threadIdx.x;
  int t = idx >> 9, d = idx & 511;
  float acc = b_dt[d];
  #pragma unroll
  for (int r = 0; r < 16; ++r) acc += dbc[t * 48 + r] * w_dt[r * 512 + d];
  dt[idx] = (acc > 20.f) ? acc : __logf(1.f + __expf(acc));
}

// ---------------- selective scan, chunked (128 chunks x 32 steps) ----------------
// phase 1: local scan from zero state; emit per-chunk carry (decay = exp(A*sum_dt), h_end)
__global__ __launch_bounds__(256) void scan_p1_k(const float* __restrict__ dt,
    const float* __restrict__ u, const float* __restrict__ dbc, const float* __restrict__ A_log,
    float* __restrict__ dAc, float* __restrict__ hend){
  __shared__ float Bl[32 * 16];
  const int c = blockIdx.x;
  const int d = blockIdx.y * 256 + threadIdx.x;
  for (int i = threadIdx.x; i < 512; i += 256)
    Bl[i] = dbc[(size_t)(c * 32 + (i >> 4)) * 48 + 16 + (i & 15)];
  __syncthreads();
  float Aa[16], h[16];
  #pragma unroll
  for (int s = 0; s < 16; ++s){ Aa[s] = -__expf(A_log[d * 16 + s]); h[s] = 0.f; }
  float ds = 0.f;
  for (int t = 0; t < 32; ++t){
    int gt = c * 32 + t;
    float ldt = dt[(size_t)gt * 512 + d];
    float lu  = u [(size_t)gt * 512 + d];
    float dtu = ldt * lu;
    ds += ldt;
    #pragma unroll
    for (int s = 0; s < 16; ++s)
      h[s] = __expf(ldt * Aa[s]) * h[s] + dtu * Bl[t * 16 + s];
  }
  #pragma unroll
  for (int s = 0; s < 16; ++s){
    size_t rec = (size_t)c * 8192 + s * 512 + d;
    dAc[rec]  = __expf(ds * Aa[s]);
    hend[rec] = h[s];
  }
}

// phase 2: sequential carry propagation across 128 chunks; 4 chains/thread for ILP.
__global__ __launch_bounds__(256) void scan_p2_k(const float* __restrict__ dAc,
    const float* __restrict__ hend, float* __restrict__ carry){
  int g = blockIdx.x * 256 + threadIdx.x;   // 0..2047
  float h0 = 0.f, h1 = 0.f, h2 = 0.f, h3 = 0.f;
  for (int c = 0; c < 128; ++c){
    size_t b = (size_t)c * 8192 + g;
    float a0 = dAc[b], a1 = dAc[b + 2048], a2 = dAc[b + 4096], a3 = dAc[b + 6144];
    float e0 = hend[b], e1 = hend[b + 2048], e2 = hend[b + 4096], e3 = hend[b + 6144];
    carry[b] = h0; carry[b + 2048] = h1; carry[b + 4096] = h2; carry[b + 6144] = h3;
    h0 = fmaf(a0, h0, e0); h1 = fmaf(a1, h1, e1);
    h2 = fmaf(a2, h2, e2); h3 = fmaf(a3, h3, e3);
  }
}

// phase 3: rescan with carry-in, fused y = sum_s h*C, + u*D_skip, * silu(z)
__global__ __launch_bounds__(256) void scan_p3_k(const float* __restrict__ dt,
    const float* __restrict__ u, const float* __restrict__ z, const float* __restrict__ dbc,
    const float* __restrict__ A_log, const float* __restrict__ Dsk,
    const float* __restrict__ carry, float* __restrict__ yf){
  __shared__ float Bl[32 * 16];
  __shared__ float Cl[32 * 16];
  const int c = blockIdx.x;
  const int d = blockIdx.y * 256 + threadIdx.x;
  for (int i = threadIdx.x; i < 512; i += 256){
    size_t rowb = (size_t)(c * 32 + (i >> 4)) * 48;
    Bl[i] = dbc[rowb + 16 + (i & 15)];
    Cl[i] = dbc[rowb + 32 + (i & 15)];
  }
  __syncthreads();
  float Aa[16], h[16];
  #pragma unroll
  for (int s = 0; s < 16; ++s){
    Aa[s] = -__expf(A_log[d * 16 + s]);
    h[s]  = carry[(size_t)c * 8192 + s * 512 + d];
  }
  const float dsk = Dsk[d];
  for (int t = 0; t < 32; ++t){
    int gt = c * 32 + t;
    float ldt = dt[(size_t)gt * 512 + d];
    float lu  = u [(size_t)gt * 512 + d];
    float lz  = z [(size_t)gt * 512 + d];
    float dtu = ldt * lu;
    float y = 0.f;
    #pragma unroll
    for (int s = 0; s < 16; ++s){
      h[s] = __expf(ldt * Aa[s]) * h[s] + dtu * Bl[t * 16 + s];
      y = fmaf(h[s], Cl[t * 16 + s], y);
    }
    yf[(size_t)gt * 512 + d] = (y + lu * dsk) * silu_f(lz);
  }
}

extern "C" void kernel_launch(void* const* d_in, const int* in_sizes, int n_in,
                              void* d_out, int out_size, void* d_ws, size_t ws_size,
                              hipStream_t stream){
  const float* x      = (const float*)d_in[0];
  const float* adj    = (const float*)d_in[1];
  const float* gcn_w  = (const float*)d_in[2];
  const float* gcn_b  = (const float*)d_in[3];
  const float* ln_g   = (const float*)d_in[4];
  const float* ln_b   = (const float*)d_in[5];
  const float* w_in   = (const float*)d_in[6];
  const float* conv_w = (const float*)d_in[7];
  const float* conv_b = (const float*)d_in[8];
  const float* w_xp   = (const float*)d_in[9];
  const float* w_dt   = (const float*)d_in[10];
  const float* b_dt   = (const float*)d_in[11];
  const float* A_log  = (const float*)d_in[12];
  const float* D_skip = (const float*)d_in[13];
  const float* w_out  = (const float*)d_in[14];
  float* out = (float*)d_out;

  char* w = (char*)d_ws;                       // ~50 MB total (with overlays)
  u16*   xT     = (u16*)(w);                   // 256x4096 bf16
  u16*   gcnT   = (u16*)(w + 2097152);         // 256x256
  u16*   w_inT  = (u16*)(w + 2228224);         // 1024x256
  u16*   w_outT = (u16*)(w + 2752512);         // 256x512
  u16*   w_xpT  = (u16*)(w + 3014656);         // 64x512 (rows 48..63 zero-padded)
  float* G      = (float*)(w + 3080192);       // 4096x256   (dead after K3 -> reused as dAc)
  float* hn     = (float*)(w + 7274496);       // 4096x256   (dead after K4 -> reused as hend)
  float* xc     = (float*)(w + 11468800);      // 4096x512   (dead after K5 -> reused as yf)
  float* zb     = (float*)(w + 19857408);      // 4096x512
  float* ub     = (float*)(w + 28246016);      // 4096x512
  float* dbc    = (float*)(w + 36634624);      // 4096x48
  float* dtb    = (float*)(w + 37421056);      // 4096x512
  float* carry  = (float*)(w + 45809664);      // 128x8192
  float* dAc    = G;
  float* hendb  = hn;
  float* yf     = xc;

  hipMemsetAsync(G,     0, (size_t)4096 * 256 * 4, stream);
  hipMemsetAsync(out,   0, (size_t)4096 * 256 * 4, stream);
  hipMemsetAsync(w_xpT, 0, (size_t)64 * 512 * 2, stream);

  dim3 tb(32, 8);
  transpose_bf16_k<<<dim3(8, 128), tb, 0, stream>>>(x,      xT,     4096, 256);
  transpose_bf16_k<<<dim3(8, 8),   tb, 0, stream>>>(gcn_w,  gcnT,   256,  256);
  transpose_bf16_k<<<dim3(32, 8),  tb, 0, stream>>>(w_in,   w_inT,  256,  1024);
  transpose_bf16_k<<<dim3(8, 16),  tb, 0, stream>>>(w_out,  w_outT, 512,  256);
  transpose_bf16_k<<<dim3(2, 16),  tb, 0, stream>>>(w_xp,   w_xpT,  512,  48);

  // K1: G = adj @ x   (M=4096,K=4096,N=256) split-K=4, atomic accumulate
  gemm_k<0, 64, 256><<<dim3(64, 1, 4), 256, 25600, stream>>>(
      adj, 4096, xT, 4096, 1024, G, nullptr, nullptr, nullptr, nullptr);
  // K3: hn = LN(relu(G @ gcn_w + gcn_b))
  gemm_k<1, 32, 256><<<dim3(128, 1, 1), 256, 56192, stream>>>(
      G, 256, gcnT, 256, 256, hn, nullptr, gcn_b, ln_g, ln_b);
  // K4: xz = hn @ w_in -> xc | z
  gemm_k<2, 64, 256><<<dim3(64, 4, 1), 256, 25600, stream>>>(
      hn, 256, w_inT, 256, 256, xc, zb, nullptr, nullptr, nullptr);
  // K5: u = silu(depthwise_conv(xc))
  conv_silu_k<<<8192, 256, 0, stream>>>(xc, conv_w, conv_b, ub);
  // K6: dbc = u @ w_xp  (N=48 padded to 64)
  gemm_k<3, 32, 64><<<dim3(128, 1, 1), 256, 7680, stream>>>(
      ub, 512, w_xpT, 512, 512, dbc, nullptr, nullptr, nullptr, nullptr);
  // K7: dt = softplus(dbc[:, :16] @ w_dt + b_dt)
  dt_k<<<8192, 256, 0, stream>>>(dbc, w_dt, b_dt, dtb);
  // K8-K10: chunked selective scan
  scan_p1_k<<<dim3(128, 2), 256, 0, stream>>>(dtb, ub, dbc, A_log, dAc, hendb);
  scan_p2_k<<<8, 256, 0, stream>>>(dAc, hendb, carry);
  scan_p3_k<<<dim3(128, 2), 256, 0, stream>>>(dtb, ub, zb, dbc, A_log, D_skip, carry, yf);
  // K11: out = yf @ w_out  (M=4096,K=512,N=256) split-K=4, atomic
  gemm_k<0, 64, 256><<<dim3(64, 1, 4), 256, 25600, stream>>>(
      yf, 512, w_outT, 512, 128, out, nullptr, nullptr, nullptr, nullptr);
}